// Round 4
// baseline (299.775 us; speedup 1.0000x reference)
//
#include <hip/hip_runtime.h>

#define N_NODES 200000
#define N_EDGES 6400000
#define IN_DIM 15
#define POS_DIM 4

#define CSHIFT 9
#define CMASK 511
#define CW 512                                      // nodes per coarse bucket
#define NCOARSE ((N_NODES + CW - 1) >> CSHIFT)      // 391
#define CHUNK 16384                                 // edges per scatter block
#define NBLK ((N_EDGES + CHUNK - 1) / CHUNK)        // 391
#define CAP 17408                                   // per-bucket region capacity (mean 16384 + 8 sigma)

typedef unsigned uv4 __attribute__((ext_vector_type(4)));

// ---------------- Pass A: per-node j-side table (+ gcnt zero) ----------------
__global__ void node_prep(const float* __restrict__ x,
                          const float* __restrict__ Wlin,
                          const float* __restrict__ Wsrc,
                          const float* __restrict__ Wpos,
                          float4* __restrict__ tabJ,
                          unsigned* __restrict__ gcnt)
{
    int n = blockIdx.x * blockDim.x + threadIdx.x;
    if (n < NCOARSE) gcnt[n] = 0u;                  // zero bucket counters inline
    if (n >= N_NODES) return;
    const float* xp = x + (long)n * IN_DIM;
    float xv[IN_DIM];
#pragma unroll
    for (int k = 0; k < IN_DIM; ++k) xv[k] = xp[k];

    float p0 = 0.f, p1 = 0.f;
#pragma unroll
    for (int k = 0; k < POS_DIM; ++k) {
        p0 += Wpos[k] * xv[k];
        p1 += Wpos[POS_DIM + k] * xv[k];
    }
    float v0 = 0.f, v1 = 0.f, as0 = 0.f, as1 = 0.f;
#pragma unroll
    for (int k = 0; k < IN_DIM; ++k) {
        float xk = xv[k];
        v0  += Wlin[k] * xk;  v1  += Wlin[IN_DIM + k] * xk;
        as0 += Wsrc[k] * xk;  as1 += Wsrc[IN_DIM + k] * xk;
    }
    tabJ[n] = make_float4(as0 + p0, as1 + p1, v0 - p0, v1 - p1);
}

// ---------------- K1: LDS-staged scatter with atomic bucket reservation -----
// Each block reserves its per-bucket span via one global atomicAdd per
// (block,bucket). Placement order within a bucket is arbitrary -- the
// aggregation is order-independent (DS float atomics).
__global__ void scatter_kernel(const int* __restrict__ idx,
                               unsigned* __restrict__ gcnt,
                               unsigned* __restrict__ packed)
{
    __shared__ unsigned stage[CHUNK];        // 64 KB
    __shared__ unsigned cnt[512];            // counts -> cur
    __shared__ unsigned sc[512];             // scan workspace
    __shared__ unsigned lloc[512];           // exclusive local starts
    __shared__ unsigned gdst[NCOARSE];       // this block's offset within bucket
    int b = blockIdx.x;
    int t = threadIdx.x;                     // 512 threads (8 waves)
    long s0 = (long)b * CHUNK;
    int end = (int)min((long)CHUNK, (long)N_EDGES - s0);   // %2048==0
    cnt[t] = 0u;
    __syncthreads();
    // pass 1: local histogram
    for (int e = t * 4; e < end; e += 2048) {
        int4 iv = *(const int4*)(idx + s0 + e);
        atomicAdd(&cnt[iv.x >> CSHIFT], 1u);
        atomicAdd(&cnt[iv.y >> CSHIFT], 1u);
        atomicAdd(&cnt[iv.z >> CSHIFT], 1u);
        atomicAdd(&cnt[iv.w >> CSHIFT], 1u);
    }
    __syncthreads();
    // inclusive scan over 512 (1 elem/thread)
    sc[t] = cnt[t];
    __syncthreads();
    for (int o = 1; o < 512; o <<= 1) {
        unsigned a = (t >= o) ? sc[t - o] : 0u;
        __syncthreads();
        sc[t] += a;
        __syncthreads();
    }
    {
        unsigned c  = cnt[t];
        unsigned ex = sc[t] - c;             // exclusive local start
        lloc[t] = ex;
        if (t < NCOARSE) gdst[t] = atomicAdd(&gcnt[t], c);  // reserve span
        cnt[t] = ex;                         // cnt becomes cur (own entry only)
    }
    __syncthreads();
    // pass 2: place into LDS stage, bucket-major
    for (int e = t * 4; e < end; e += 2048) {
        int4 iv = *(const int4*)(idx + s0 + e);
        int4 jv = *(const int4*)(idx + N_EDGES + s0 + e);
        unsigned r0 = atomicAdd(&cnt[iv.x >> CSHIFT], 1u);
        unsigned r1 = atomicAdd(&cnt[iv.y >> CSHIFT], 1u);
        unsigned r2 = atomicAdd(&cnt[iv.z >> CSHIFT], 1u);
        unsigned r3 = atomicAdd(&cnt[iv.w >> CSHIFT], 1u);
        stage[r0] = ((unsigned)jv.x << CSHIFT) | (unsigned)(iv.x & CMASK);
        stage[r1] = ((unsigned)jv.y << CSHIFT) | (unsigned)(iv.y & CMASK);
        stage[r2] = ((unsigned)jv.z << CSHIFT) | (unsigned)(iv.z & CMASK);
        stage[r3] = ((unsigned)jv.w << CSHIFT) | (unsigned)(iv.w & CMASK);
    }
    __syncthreads();
    // pass 3: dense copy-out, one wave per bucket run (8 waves)
    int wid = t >> 6, lane = t & 63;
    for (int bk = wid; bk < NCOARSE; bk += 8) {
        unsigned st  = lloc[bk];
        unsigned len = lloc[bk + 1] - st;            // bk+1 <= 391 < 512
        unsigned gb  = gdst[bk];
        unsigned rem = (gb < (unsigned)CAP) ? (unsigned)CAP - gb : 0u;
        if (len > rem) len = rem;                    // loud-fail clamp, never hit
        unsigned* dst = packed + (size_t)bk * CAP + gb;
        for (unsigned e = lane; e < len; e += 64u)
            dst[e] = stage[st + e];
    }
}

// ---------------- K2: streaming aggregate via raw ds_add_f32 ----------------
// Round-3 post-mortem: __hip_atomic_fetch_add stalled both pipes (178us,
// VALU 1.6%) -- it did not lower to plain ds_add_f32. Emit the HW primitive
// directly. accC is component-major [4][512] so each ds_add_f32 instruction
// spreads random node ids across all 32 banks; the 4 components of one edge
// are reached via the free 16-bit offset: immediate.

__device__ __forceinline__ void acc4_add(unsigned addr,
                                         float d0, float d1, float n0, float n1)
{
    // no "memory" clobber: keeps next iteration's gathers hoistable; ordering
    // vs the final accumulator reads is enforced by the fence before barrier.
    asm volatile("ds_add_f32 %0, %1"              :: "v"(addr), "v"(d0));
    asm volatile("ds_add_f32 %0, %1 offset:2048"  :: "v"(addr), "v"(d1));
    asm volatile("ds_add_f32 %0, %1 offset:4096"  :: "v"(addr), "v"(n0));
    asm volatile("ds_add_f32 %0, %1 offset:6144"  :: "v"(addr), "v"(n1));
}

__global__ __launch_bounds__(512) void
bucket_agg_kernel(const unsigned* __restrict__ packed,
                  const unsigned* __restrict__ gcnt,
                  const float* __restrict__ x,
                  const float* __restrict__ Wdst,
                  const float* __restrict__ Wpos,
                  const float4* __restrict__ tabJ,
                  const float* __restrict__ bpos,
                  float2* __restrict__ out)
{
    __shared__ float2 als[512];      // A_i = a_dst_i + p_i + b  (read-only after init)
    __shared__ float  accC[4][512];  // component-major: d0 | d1 | n0 | n1
    int k = blockIdx.x;
    int t = threadIdx.x;
    float b0 = bpos[0], b1 = bpos[1];
    int gn = (k << CSHIFT) + t;

    float p0 = 0.f, p1 = 0.f, ad0 = 0.f, ad1 = 0.f;
    if (gn < N_NODES) {
        const float* xp = x + (long)gn * IN_DIM;
        float xv[IN_DIM];
#pragma unroll
        for (int q = 0; q < IN_DIM; ++q) xv[q] = xp[q];
#pragma unroll
        for (int q = 0; q < POS_DIM; ++q) {
            p0 += Wpos[q] * xv[q];
            p1 += Wpos[POS_DIM + q] * xv[q];
        }
#pragma unroll
        for (int q = 0; q < IN_DIM; ++q) {
            ad0 += Wdst[q] * xv[q];
            ad1 += Wdst[IN_DIM + q] * xv[q];
        }
    }
    als[t] = make_float2(ad0 + p0 + b0, ad1 + p1 + b1);
    accC[0][t] = 0.f; accC[1][t] = 0.f; accC[2][t] = 0.f; accC[3][t] = 0.f;
    __syncthreads();

    unsigned accBase = (unsigned)(unsigned long long)&accC[0][0];  // LDS byte offset
    unsigned n = min(gcnt[k], (unsigned)CAP);     // loud-fail clamp, never hit
    const unsigned* pk = packed + (size_t)k * CAP;

    for (unsigned e = 4u * t; e < n; e += 2048u) {
        uv4 p = __builtin_nontemporal_load((const uv4*)(pk + e));   // 16B-aligned region
        if (e + 4u <= n) {
            unsigned r0 = p.x & CMASK, r1 = p.y & CMASK, r2 = p.z & CMASK, r3 = p.w & CMASK;
            float4 f0 = tabJ[p.x >> CSHIFT];   // 4 independent L2 gathers issue together
            float4 f1 = tabJ[p.y >> CSHIFT];
            float4 f2 = tabJ[p.z >> CSHIFT];
            float4 f3 = tabJ[p.w >> CSHIFT];
            float2 a0 = als[r0], a1 = als[r1], a2 = als[r2], a3 = als[r3];
            float e00 = __expf(a0.x - f0.x), e01 = __expf(a0.y - f0.y);
            float e10 = __expf(a1.x - f1.x), e11 = __expf(a1.y - f1.y);
            float e20 = __expf(a2.x - f2.x), e21 = __expf(a2.y - f2.y);
            float e30 = __expf(a3.x - f3.x), e31 = __expf(a3.y - f3.y);
            acc4_add(accBase + (r0 << 2), e00, e01, e00 * f0.z, e01 * f0.w);
            acc4_add(accBase + (r1 << 2), e10, e11, e10 * f1.z, e11 * f1.w);
            acc4_add(accBase + (r2 << 2), e20, e21, e20 * f2.z, e21 * f2.w);
            acc4_add(accBase + (r3 << 2), e30, e31, e30 * f3.z, e31 * f3.w);
        } else {
            for (unsigned q = 0; q < 3u; ++q) {
                if (e + q >= n) break;
                unsigned w = (q == 0) ? p.x : (q == 1) ? p.y : p.z;
                unsigned r = w & CMASK;
                float4 fj = tabJ[w >> CSHIFT];
                float2 a = als[r];
                float e0 = __expf(a.x - fj.x), e1 = __expf(a.y - fj.y);
                acc4_add(accBase + (r << 2), e0, e1, e0 * fj.z, e1 * fj.w);
            }
        }
    }
    // all our ds_add_f32 are lgkm ops: drain them, then barrier, then read.
    asm volatile("s_waitcnt lgkmcnt(0)" ::: "memory");
    __syncthreads();

    if (gn >= N_NODES) return;
    float sd0 = accC[0][t], sd1 = accC[1][t], sn0 = accC[2][t], sn1 = accC[3][t];
    float o0 = (sn0 + (p0 + b0) * sd0) / (sd0 + 1e-16f);
    float o1 = (sn1 + (p1 + b1) * sd1) / (sd1 + 1e-16f);
    out[gn] = make_float2(o0, o1);
}

extern "C" void kernel_launch(void* const* d_in, const int* in_sizes, int n_in,
                              void* d_out, int out_size, void* d_ws, size_t ws_size,
                              hipStream_t stream) {
    const float* x    = (const float*)d_in[0];
    const int*   idx  = (const int*)d_in[1];   // (2, E) flat: [0..E)=i, [E..2E)=j
    const float* Wlin = (const float*)d_in[2];
    const float* Wsrc = (const float*)d_in[3];
    const float* Wdst = (const float*)d_in[4];
    const float* Wpos = (const float*)d_in[5];
    const float* bpos = (const float*)d_in[6];
    float* out = (float*)d_out;

    char* ws = (char*)d_ws;
    size_t off = 0;
    float4* tabJ = (float4*)(ws + off); off += (size_t)N_NODES * 16;        //  3.2 MB
    unsigned* packed = (unsigned*)(ws + off); off += (size_t)NCOARSE * CAP * 4;  // 27.2 MB
    unsigned* gcnt   = (unsigned*)(ws + off); off += (size_t)NCOARSE * 4;   // total ~30.4 MB (< proven 32.6)

    node_prep<<<(N_NODES + 255) / 256, 256, 0, stream>>>(x, Wlin, Wsrc, Wpos,
                                                         tabJ, gcnt);
    scatter_kernel<<<NBLK, 512, 0, stream>>>(idx, gcnt, packed);
    bucket_agg_kernel<<<NCOARSE, 512, 0, stream>>>(packed, gcnt,
                                                   x, Wdst, Wpos, tabJ, bpos,
                                                   (float2*)out);
}

// Round 5
// 169.791 us; speedup vs baseline: 1.7656x; 1.7656x over previous
//
#include <hip/hip_runtime.h>

#define N_NODES 200000
#define N_EDGES 6400000
#define IN_DIM 15
#define POS_DIM 4

#define CSHIFT 9
#define CMASK 511
#define CW 512                                      // nodes per coarse bucket
#define NCOARSE ((N_NODES + CW - 1) >> CSHIFT)      // 391
#define CHUNK 16384                                 // edges per scatter block
#define NBLK ((N_EDGES + CHUNK - 1) / CHUNK)        // 391
#define CAP 17408                                   // per-bucket region capacity (mean 16384 + 8 sigma)
#define SUB 8192                                    // agg sub-chunk (LDS 40KB -> 4 blocks/CU)

typedef unsigned uv4 __attribute__((ext_vector_type(4)));

// MEASURED (r3/r4): divergent-address ds_add_f32 ~ 4.3 cy/lane (per-lane
// serialized, pipes idle). u32 LDS atomicAdd ~ <=1 cy/lane (r0). So the
// aggregation uses u32-atomic counting sort + register accumulation, never
// per-edge f32 atomics.

// ---------------- Pass A: per-node j-side table (+ gcnt zero) ----------------
__global__ void node_prep(const float* __restrict__ x,
                          const float* __restrict__ Wlin,
                          const float* __restrict__ Wsrc,
                          const float* __restrict__ Wpos,
                          float4* __restrict__ tabJ,
                          unsigned* __restrict__ gcnt)
{
    int n = blockIdx.x * blockDim.x + threadIdx.x;
    if (n < NCOARSE) gcnt[n] = 0u;                  // zero bucket counters inline
    if (n >= N_NODES) return;
    const float* xp = x + (long)n * IN_DIM;
    float xv[IN_DIM];
#pragma unroll
    for (int k = 0; k < IN_DIM; ++k) xv[k] = xp[k];

    float p0 = 0.f, p1 = 0.f;
#pragma unroll
    for (int k = 0; k < POS_DIM; ++k) {
        p0 += Wpos[k] * xv[k];
        p1 += Wpos[POS_DIM + k] * xv[k];
    }
    float v0 = 0.f, v1 = 0.f, as0 = 0.f, as1 = 0.f;
#pragma unroll
    for (int k = 0; k < IN_DIM; ++k) {
        float xk = xv[k];
        v0  += Wlin[k] * xk;  v1  += Wlin[IN_DIM + k] * xk;
        as0 += Wsrc[k] * xk;  as1 += Wsrc[IN_DIM + k] * xk;
    }
    tabJ[n] = make_float4(as0 + p0, as1 + p1, v0 - p0, v1 - p1);
}

// ---------------- K1: LDS-staged scatter with atomic bucket reservation -----
// Each block reserves its per-bucket span via one global atomicAdd per
// (block,bucket). Placement order within a bucket is arbitrary -- the
// aggregation is order-independent.
__global__ void scatter_kernel(const int* __restrict__ idx,
                               unsigned* __restrict__ gcnt,
                               unsigned* __restrict__ packed)
{
    __shared__ unsigned stage[CHUNK];        // 64 KB
    __shared__ unsigned cnt[512];            // counts -> cur
    __shared__ unsigned sc[512];             // scan workspace
    __shared__ unsigned lloc[512];           // exclusive local starts
    __shared__ unsigned gdst[NCOARSE];       // this block's offset within bucket
    int b = blockIdx.x;
    int t = threadIdx.x;                     // 512 threads (8 waves)
    long s0 = (long)b * CHUNK;
    int end = (int)min((long)CHUNK, (long)N_EDGES - s0);   // %2048==0
    cnt[t] = 0u;
    __syncthreads();
    // pass 1: local histogram
    for (int e = t * 4; e < end; e += 2048) {
        int4 iv = *(const int4*)(idx + s0 + e);
        atomicAdd(&cnt[iv.x >> CSHIFT], 1u);
        atomicAdd(&cnt[iv.y >> CSHIFT], 1u);
        atomicAdd(&cnt[iv.z >> CSHIFT], 1u);
        atomicAdd(&cnt[iv.w >> CSHIFT], 1u);
    }
    __syncthreads();
    // inclusive scan over 512 (1 elem/thread)
    sc[t] = cnt[t];
    __syncthreads();
    for (int o = 1; o < 512; o <<= 1) {
        unsigned a = (t >= o) ? sc[t - o] : 0u;
        __syncthreads();
        sc[t] += a;
        __syncthreads();
    }
    {
        unsigned c  = cnt[t];
        unsigned ex = sc[t] - c;             // exclusive local start
        lloc[t] = ex;
        if (t < NCOARSE) gdst[t] = atomicAdd(&gcnt[t], c);  // reserve span
        cnt[t] = ex;                         // cnt becomes cur (own entry only)
    }
    __syncthreads();
    // pass 2: place into LDS stage, bucket-major
    for (int e = t * 4; e < end; e += 2048) {
        int4 iv = *(const int4*)(idx + s0 + e);
        int4 jv = *(const int4*)(idx + N_EDGES + s0 + e);
        unsigned r0 = atomicAdd(&cnt[iv.x >> CSHIFT], 1u);
        unsigned r1 = atomicAdd(&cnt[iv.y >> CSHIFT], 1u);
        unsigned r2 = atomicAdd(&cnt[iv.z >> CSHIFT], 1u);
        unsigned r3 = atomicAdd(&cnt[iv.w >> CSHIFT], 1u);
        stage[r0] = ((unsigned)jv.x << CSHIFT) | (unsigned)(iv.x & CMASK);
        stage[r1] = ((unsigned)jv.y << CSHIFT) | (unsigned)(iv.y & CMASK);
        stage[r2] = ((unsigned)jv.z << CSHIFT) | (unsigned)(iv.z & CMASK);
        stage[r3] = ((unsigned)jv.w << CSHIFT) | (unsigned)(iv.w & CMASK);
    }
    __syncthreads();
    // pass 3: dense copy-out, one wave per bucket run (8 waves)
    int wid = t >> 6, lane = t & 63;
    for (int bk = wid; bk < NCOARSE; bk += 8) {
        unsigned st  = lloc[bk];
        unsigned len = lloc[bk + 1] - st;            // bk+1 <= 391 < 512
        unsigned gb  = gdst[bk];
        unsigned rem = (gb < (unsigned)CAP) ? (unsigned)CAP - gb : 0u;
        if (len > rem) len = rem;                    // loud-fail clamp, never hit
        unsigned* dst = packed + (size_t)bk * CAP + gb;
        for (unsigned e = lane; e < len; e += 64u)
            dst[e] = stage[st + e];
    }
}

// ---------------- K2: chunked counting-sort + register aggregation ----------
// Round-0-proven instruction mix (u32 LDS atomics for sort, register agg),
// restructured into SUB=8192-edge chunks so LDS = 40KB -> 4 blocks/CU
// (was 76KB -> 2 blocks/CU at 44.8us). Per-thread accumulators carry across
// chunks in registers.
__global__ __launch_bounds__(512, 8) void
bucket_agg_kernel(const unsigned* __restrict__ packed,
                  const unsigned* __restrict__ gcnt,
                  const float* __restrict__ x,
                  const float* __restrict__ Wdst,
                  const float* __restrict__ Wpos,
                  const float4* __restrict__ tabJ,
                  const float* __restrict__ bpos,
                  float2* __restrict__ out)
{
    __shared__ unsigned cache[SUB + 512];    // node-major j values (+lane stagger)
    __shared__ unsigned cnt[512], sc[512], cur[512];   // total LDS = 40 KB
    int k = blockIdx.x;
    int t = threadIdx.x;                     // 1 node per thread
    float b0 = bpos[0], b1 = bpos[1];
    int gn = (k << CSHIFT) + t;

    // own-node logits, recomputed from x (tabI/pvec buffers eliminated)
    float p0 = 0.f, p1 = 0.f, ad0 = 0.f, ad1 = 0.f;
    if (gn < N_NODES) {
        const float* xp = x + (long)gn * IN_DIM;
        float xv[IN_DIM];
#pragma unroll
        for (int q = 0; q < IN_DIM; ++q) xv[q] = xp[q];
#pragma unroll
        for (int q = 0; q < POS_DIM; ++q) {
            p0 += Wpos[q] * xv[q];
            p1 += Wpos[POS_DIM + q] * xv[q];
        }
#pragma unroll
        for (int q = 0; q < IN_DIM; ++q) {
            ad0 += Wdst[q] * xv[q];
            ad1 += Wdst[IN_DIM + q] * xv[q];
        }
    }
    float a0 = ad0 + p0 + b0, a1 = ad1 + p1 + b1;    // A_i (registers only)
    float sn0 = 0.f, sn1 = 0.f, sd0 = 0.f, sd1 = 0.f;

    unsigned n = min(gcnt[k], (unsigned)CAP);        // loud-fail clamp, never hit
    const unsigned* pk = packed + (size_t)k * CAP;

    for (unsigned c0 = 0; c0 < n; c0 += SUB) {
        unsigned m = min(n - c0, (unsigned)SUB);
        cnt[t] = 0u;
        __syncthreads();     // also orders prev chunk's cache reads before this place
        // pass 1: histogram of low 9 bits
        for (unsigned e = 4u * t; e < m; e += 2048u) {
            uv4 p = *(const uv4*)(pk + c0 + e);      // aligned 16B, stays in CAP region
            atomicAdd(&cnt[p.x & CMASK], 1u);
            if (e + 1 < m) atomicAdd(&cnt[p.y & CMASK], 1u);
            if (e + 2 < m) atomicAdd(&cnt[p.z & CMASK], 1u);
            if (e + 3 < m) atomicAdd(&cnt[p.w & CMASK], 1u);
        }
        __syncthreads();
        // inclusive scan over 512
        sc[t] = cnt[t];
        __syncthreads();
        for (int o = 1; o < 512; o <<= 1) {
            unsigned a = (t >= o) ? sc[t - o] : 0u;
            __syncthreads();
            sc[t] += a;
            __syncthreads();
        }
        unsigned deg = cnt[t];
        unsigned st  = sc[t] - deg + (unsigned)t;    // +lane stagger breaks bank pattern
        cur[t] = st;
        __syncthreads();
        // pass 2: place bare j into LDS, node-major (chunk is L2-hot from pass 1)
        for (unsigned e = 4u * t; e < m; e += 2048u) {
            uv4 p = *(const uv4*)(pk + c0 + e);
            { unsigned pos = atomicAdd(&cur[p.x & CMASK], 1u); cache[pos] = p.x >> CSHIFT; }
            if (e + 1 < m) { unsigned pos = atomicAdd(&cur[p.y & CMASK], 1u); cache[pos] = p.y >> CSHIFT; }
            if (e + 2 < m) { unsigned pos = atomicAdd(&cur[p.z & CMASK], 1u); cache[pos] = p.z >> CSHIFT; }
            if (e + 3 < m) { unsigned pos = atomicAdd(&cur[p.w & CMASK], 1u); cache[pos] = p.w >> CSHIFT; }
        }
        __syncthreads();
        // pass 3: per-node register aggregation over this chunk's run
        unsigned e = 0;
        for (; e + 4u <= deg; e += 4u) {
            unsigned j0 = cache[st + e],     j1 = cache[st + e + 1];
            unsigned j2 = cache[st + e + 2], j3 = cache[st + e + 3];
            float4 f0 = tabJ[j0], f1 = tabJ[j1], f2 = tabJ[j2], f3 = tabJ[j3];
            float e00 = __expf(a0 - f0.x), e01 = __expf(a1 - f0.y);
            float e10 = __expf(a0 - f1.x), e11 = __expf(a1 - f1.y);
            float e20 = __expf(a0 - f2.x), e21 = __expf(a1 - f2.y);
            float e30 = __expf(a0 - f3.x), e31 = __expf(a1 - f3.y);
            sn0 += e00 * f0.z + e10 * f1.z + e20 * f2.z + e30 * f3.z;
            sn1 += e01 * f0.w + e11 * f1.w + e21 * f2.w + e31 * f3.w;
            sd0 += e00 + e10 + e20 + e30;
            sd1 += e01 + e11 + e21 + e31;
        }
        for (; e < deg; ++e) {
            unsigned j = cache[st + e];
            float4 fj = tabJ[j];
            float e0 = __expf(a0 - fj.x), e1 = __expf(a1 - fj.y);
            sn0 += e0 * fj.z;  sn1 += e1 * fj.w;
            sd0 += e0;         sd1 += e1;
        }
        // no trailing barrier: next iteration's cnt-reset barrier orders
        // these cache reads before the next place pass's cache writes.
    }

    if (gn >= N_NODES) return;
    float o0 = (sn0 + (p0 + b0) * sd0) / (sd0 + 1e-16f);
    float o1 = (sn1 + (p1 + b1) * sd1) / (sd1 + 1e-16f);
    out[gn] = make_float2(o0, o1);
}

extern "C" void kernel_launch(void* const* d_in, const int* in_sizes, int n_in,
                              void* d_out, int out_size, void* d_ws, size_t ws_size,
                              hipStream_t stream) {
    const float* x    = (const float*)d_in[0];
    const int*   idx  = (const int*)d_in[1];   // (2, E) flat: [0..E)=i, [E..2E)=j
    const float* Wlin = (const float*)d_in[2];
    const float* Wsrc = (const float*)d_in[3];
    const float* Wdst = (const float*)d_in[4];
    const float* Wpos = (const float*)d_in[5];
    const float* bpos = (const float*)d_in[6];
    float* out = (float*)d_out;

    char* ws = (char*)d_ws;
    size_t off = 0;
    float4* tabJ = (float4*)(ws + off); off += (size_t)N_NODES * 16;        //  3.2 MB
    unsigned* packed = (unsigned*)(ws + off); off += (size_t)NCOARSE * CAP * 4;  // 27.2 MB
    unsigned* gcnt   = (unsigned*)(ws + off); off += (size_t)NCOARSE * 4;   // total ~30.4 MB (< proven 32.6)

    node_prep<<<(N_NODES + 255) / 256, 256, 0, stream>>>(x, Wlin, Wsrc, Wpos,
                                                         tabJ, gcnt);
    scatter_kernel<<<NBLK, 512, 0, stream>>>(idx, gcnt, packed);
    bucket_agg_kernel<<<NCOARSE, 512, 0, stream>>>(packed, gcnt,
                                                   x, Wdst, Wpos, tabJ, bpos,
                                                   (float2*)out);
}